// Round 7
// baseline (1169.079 us; speedup 1.0000x reference)
//
#include <hip/hip_runtime.h>
#include <hip/hip_bf16.h>

#define NN 100000
#define MM 32
#define NCAPS_ 8
#define HH 64
#define FAN 512  // NCAPS*H

typedef __attribute__((ext_vector_type(8))) short bf16x8;
typedef __attribute__((ext_vector_type(4))) float f32x4;

__device__ inline short f2bf(float f) {
  union { float f; unsigned u; } v; v.f = f;
  unsigned u = v.u;
  u += 0x7FFFu + ((u >> 16) & 1u);   // round-to-nearest-even
  return (short)(u >> 16);
}

__device__ inline bf16x8 cvt8(f32x4 lo, f32x4 hi) {
  bf16x8 r;
  r[0] = f2bf(lo[0]); r[1] = f2bf(lo[1]); r[2] = f2bf(lo[2]); r[3] = f2bf(lo[3]);
  r[4] = f2bf(hi[0]); r[5] = f2bf(hi[1]); r[6] = f2bf(hi[2]); r[7] = f2bf(hi[3]);
  return r;
}

// ---------------------------------------------------------------------------
// W f32 -> bf16 (once, 512 KB)
// ---------------------------------------------------------------------------
__global__ __launch_bounds__(256) void conv_kernel(
    const float* __restrict__ src, short* __restrict__ dst) {
  const int i = (blockIdx.x * 256 + threadIdx.x) * 8;
  f32x4 lo = *(const f32x4*)(src + i);
  f32x4 hi = *(const f32x4*)(src + i + 4);
  *(bf16x8*)(dst + i) = cvt8(lo, hi);
}

// ---------------------------------------------------------------------------
// Kernel A (redesigned): per-node aggregation, one wave per node.
// FAT-GATHER + LDS-ACCUMULATE:
//  - 8 gather instrs: each dwordx4 x 64 lanes covers FOUR 256-B f32 edge rows
//    (16 lanes/edge).  Edge offsets distributed from index lanes via __shfl.
//  - invalid edges (nb==NN) routed to a shared LDS dump row (no masking math).
//  - accumulation by relation via ds_add_f32 into per-wave lds[8 rel][64 feat].
//  - residual + output: full-row dwordx4 (lane = 8 feats), 2 loads + 1 store.
// VMEM/wave: 2 idx + 8 gather + 2 residual + 1 store = 13  (was 49).
// ---------------------------------------------------------------------------
__global__ __launch_bounds__(256) void agg2_kernel(
    const float* __restrict__ x,
    const int* __restrict__ nb_node,
    const int* __restrict__ nb_rel,
    unsigned short* __restrict__ vbf) {
  __shared__ float lds[4 * 512 + 64];       // 4 wave regions + shared dump row
  const int tid  = threadIdx.x;
  const int wid  = tid >> 6;                 // wave = node within block
  const int lane = tid & 63;
  const int node = blockIdx.x * 4 + wid;     // 25000*4 == NN exactly

  // zero my wave's accumulation region (512 f32, 8 per lane)
  const f32x4 z = {0.f, 0.f, 0.f, 0.f};
  *(f32x4*)(&lds[wid * 512 + lane * 8])     = z;
  *(f32x4*)(&lds[wid * 512 + lane * 8 + 4]) = z;
  asm volatile("s_waitcnt lgkmcnt(0)" ::: "memory");

  // phase 0: edge indices (lanes 32-63 duplicate lanes 0-31; harmless)
  const int e0 = node * MM + (lane & 31);
  const int nb = nb_node[e0];
  const int rl = nb_rel[e0];
  const bool valid = (nb < NN);
  const int nbc  = valid ? nb : node;
  const int goff = nbc * (FAN * 4) + rl * (HH * 4);          // byte off into x
  const int lidx = valid ? (wid * 2048 + rl * 256) : (4 * 2048); // byte off into lds

  const int src0 = lane >> 4;     // edge-group within each gather instr
  const int c16  = (lane & 15) * 16;

  const char* xb = (const char*)x;
  char* lb = (char*)lds;

#pragma unroll
  for (int i = 0; i < 8; ++i) {
    const int go = __shfl(goff, i * 4 + src0);
    const int lo = __shfl(lidx, i * 4 + src0);
    const f32x4 d = *(const f32x4*)(xb + (size_t)(unsigned)go + c16);
    float* p = (float*)(lb + lo + c16);
    atomicAdd(p + 0, d[0]);
    atomicAdd(p + 1, d[1]);
    atomicAdd(p + 2, d[2]);
    atomicAdd(p + 3, d[3]);
  }

  __syncthreads();   // all ds_adds done (own-wave only, but cheap & safe)

  // final: lane owns feats [lane*8, lane*8+8) of the node's 512-feat row
  const float* base = &lds[wid * 512 + lane * 8];
  f32x4 s0 = *(const f32x4*)(base);
  f32x4 s1 = *(const f32x4*)(base + 4);
  const float* xr = x + (size_t)node * FAN + lane * 8;
  f32x4 r0 = *(const f32x4*)(xr);
  f32x4 r1 = *(const f32x4*)(xr + 4);
#pragma unroll
  for (int j = 0; j < 4; ++j) { s0[j] += r0[j]; s1[j] += r1[j]; }
  *(bf16x8*)(vbf + (size_t)node * FAN + lane * 8) = cvt8(s0, s1);
}

// ---------------------------------------------------------------------------
// Kernel B: out = relu(vbf @ Wbf^T + b).  Unchanged from round 6 (BK=32,
// 32 KB LDS, cb-fast mapping, global_load_lds double-buffer).
// ---------------------------------------------------------------------------
#define BM 128
#define BN 128
#define BK 32
#define NRB ((NN + BM - 1) / BM)   // 782

__global__ __launch_bounds__(256) void gemm_bf_kernel(
    const short* __restrict__ vbf,   // [NN][FAN] bf16
    const short* __restrict__ Wbf,   // [FAN][FAN] bf16 (row-major W)
    const float* __restrict__ bias,
    float* __restrict__ out) {
  __shared__ short Ab[2][BM * BK];   // 2 x 8 KB
  __shared__ short Bb[2][BN * BK];   // 2 x 8 KB

  const int b  = blockIdx.x;
  const int cb = b & 3;              // fast index: col-block
  const int rb = b >> 2;

  const int tid  = threadIdx.x;
  const int lane = tid & 63;
  const int wave = tid >> 6;
  const int wr = wave >> 1, wc = wave & 1;
  const int l15 = lane & 15, kg = lane >> 4;

  const int row0 = rb * BM, col0 = cb * BN;

  f32x4 acc[4][4];
#pragma unroll
  for (int rf = 0; rf < 4; ++rf)
#pragma unroll
    for (int cf = 0; cf < 4; ++cf) acc[rf][cf] = (f32x4){0.f, 0.f, 0.f, 0.f};

  auto stage = [&](int buf, int kb) {
#pragma unroll
    for (int c = 0; c < 2; ++c) {
      const int byteoff = c * 4096 + tid * 16;
      int arow = row0 + (byteoff >> 6);
      if (arow >= NN) arow = NN - 1;             // clamp (store guarded)
      const char* asrc = (const char*)vbf + (size_t)arow * 1024 + kb * 64 + (byteoff & 63);
      char* adst = (char*)(&Ab[buf][0]) + byteoff;
      __builtin_amdgcn_global_load_lds(
          (const __attribute__((address_space(1))) void*)asrc,
          (__attribute__((address_space(3))) void*)adst, 16, 0, 0);
      const int bcol = col0 + (byteoff >> 6);
      const char* bsrc = (const char*)Wbf + (size_t)bcol * 1024 + kb * 64 + (byteoff & 63);
      char* bdst = (char*)(&Bb[buf][0]) + byteoff;
      __builtin_amdgcn_global_load_lds(
          (const __attribute__((address_space(1))) void*)bsrc,
          (__attribute__((address_space(3))) void*)bdst, 16, 0, 0);
    }
  };

  stage(0, 0);
  __syncthreads();

  int buf = 0;
  for (int kb = 0; kb < FAN / BK; ++kb) {        // 16 iterations
    if (kb + 1 < FAN / BK) stage(buf ^ 1, kb + 1);

    bf16x8 af[4], bfr[4];
#pragma unroll
    for (int rf = 0; rf < 4; ++rf)
      af[rf] = *(const bf16x8*)(&Ab[buf][(wr * 64 + rf * 16 + l15) * BK + kg * 8]);
#pragma unroll
    for (int cf = 0; cf < 4; ++cf)
      bfr[cf] = *(const bf16x8*)(&Bb[buf][(wc * 64 + cf * 16 + l15) * BK + kg * 8]);

#pragma unroll
    for (int rf = 0; rf < 4; ++rf)
#pragma unroll
      for (int cf = 0; cf < 4; ++cf)
        acc[rf][cf] = __builtin_amdgcn_mfma_f32_16x16x32_bf16(
            af[rf], bfr[cf], acc[rf][cf], 0, 0, 0);

    __syncthreads();
    buf ^= 1;
  }

  // epilogue: bias + relu + store.  D: col=l15, row=kg*4+r within frag.
#pragma unroll
  for (int cf = 0; cf < 4; ++cf) {
    const int col = col0 + wc * 64 + cf * 16 + l15;
    const float bb = bias[col];
#pragma unroll
    for (int rf = 0; rf < 4; ++rf) {
#pragma unroll
      for (int r = 0; r < 4; ++r) {
        const int row = row0 + wr * 64 + rf * 16 + kg * 4 + r;
        if (row < NN) {
          float val = acc[rf][cf][r] + bb;
          out[(size_t)row * FAN + col] = val > 0.f ? val : 0.f;
        }
      }
    }
  }
}

// ---------------------------------------------------------------------------
// Fallbacks (ws too small): old-style agg f32->f32 + f32 GEMM.
// ---------------------------------------------------------------------------
__global__ __launch_bounds__(256) void agg_fb_kernel(
    const float* __restrict__ x,
    const int* __restrict__ nb_node,
    const int* __restrict__ nb_rel,
    float* __restrict__ vf32) {
  const int wid  = __builtin_amdgcn_readfirstlane((int)(threadIdx.x >> 6));
  const int node = blockIdx.x * 4 + wid;
  const int lane = threadIdx.x & 63;

  const int eidx = node * MM + (lane & 31);
  const int pk = nb_node[eidx] | (nb_rel[eidx] << 20);

  int nbs[MM], rls[MM];
#pragma unroll
  for (int e = 0; e < MM; ++e) {
    const int p = __builtin_amdgcn_readlane(pk, e);
    nbs[e] = p & 0xFFFFF;
    rls[e] = (p >> 20) & 7;
  }

  float vf[MM];
#pragma unroll
  for (int e = 0; e < MM; ++e) {
    const int nbc = (nbs[e] < NN) ? nbs[e] : node;
    vf[e] = x[nbc * FAN + rls[e] * HH + lane];
  }
  float xr[NCAPS_];
  const int ob = node * FAN;
#pragma unroll
  for (int r = 0; r < NCAPS_; ++r) xr[r] = x[ob + r * HH + lane];

  float acc[NCAPS_];
#pragma unroll
  for (int r = 0; r < NCAPS_; ++r) acc[r] = 0.f;
#pragma unroll
  for (int e = 0; e < MM; ++e) {
    if (nbs[e] < NN) {
      const float val = vf[e];
      switch (rls[e]) {
        case 0: acc[0] += val; break;
        case 1: acc[1] += val; break;
        case 2: acc[2] += val; break;
        case 3: acc[3] += val; break;
        case 4: acc[4] += val; break;
        case 5: acc[5] += val; break;
        case 6: acc[6] += val; break;
        case 7: acc[7] += val; break;
      }
    }
  }
#pragma unroll
  for (int r = 0; r < NCAPS_; ++r)
    vf32[ob + r * HH + lane] = acc[r] + xr[r];
}

__global__ __launch_bounds__(256) void gemm_f32_kernel(
    const float* vin, const float* __restrict__ W,
    const float* __restrict__ bias, float* out) {
  const int lane = threadIdx.x & 63;
  const int wave = threadIdx.x >> 6;
  const int row0 = blockIdx.x * 64;
  const int col0 = wave * 128;
  const int l15  = lane & 15;
  const int kg   = lane >> 4;

  f32x4 acc[4][8];
#pragma unroll
  for (int rf = 0; rf < 4; ++rf)
#pragma unroll
    for (int c = 0; c < 8; ++c) acc[rf][c] = (f32x4){0.f, 0.f, 0.f, 0.f};

  for (int kb = 0; kb < FAN / 32; ++kb) {
    const int k0 = kb * 32 + kg * 8;
    bf16x8 afrag[4];
#pragma unroll
    for (int rf = 0; rf < 4; ++rf) {
      int row = row0 + rf * 16 + l15;
      if (row >= NN) row = NN - 1;
      const float* p = vin + (size_t)row * FAN + k0;
      afrag[rf] = cvt8(*(const f32x4*)p, *(const f32x4*)(p + 4));
    }
#pragma unroll
    for (int c = 0; c < 8; ++c) {
      const int col = col0 + c * 16 + l15;
      const float* q = W + (size_t)col * FAN + k0;
      bf16x8 bfrag = cvt8(*(const f32x4*)q, *(const f32x4*)(q + 4));
#pragma unroll
      for (int rf = 0; rf < 4; ++rf)
        acc[rf][c] = __builtin_amdgcn_mfma_f32_16x16x32_bf16(
            afrag[rf], bfrag, acc[rf][c], 0, 0, 0);
    }
  }

#pragma unroll
  for (int c = 0; c < 8; ++c) {
    const int col = col0 + c * 16 + l15;
    const float bb = bias[col];
#pragma unroll
    for (int rf = 0; rf < 4; ++rf)
#pragma unroll
      for (int r = 0; r < 4; ++r) {
        const int row = row0 + rf * 16 + kg * 4 + r;
        if (row < NN) {
          float val = acc[rf][c][r] + bb;
          out[(size_t)row * FAN + col] = val > 0.f ? val : 0.f;
        }
      }
  }
}

extern "C" void kernel_launch(void* const* d_in, const int* in_sizes, int n_in,
                              void* d_out, int out_size, void* d_ws, size_t ws_size,
                              hipStream_t stream) {
  const float* x  = (const float*)d_in[0];
  const float* W  = (const float*)d_in[1];
  const float* b  = (const float*)d_in[2];
  const int*   nn = (const int*)d_in[3];
  const int*   nr = (const int*)d_in[4];
  float* out = (float*)d_out;

  const size_t wbf_bytes = (size_t)FAN * FAN * sizeof(short);        // 512 KB
  const size_t vbf_bytes = (size_t)NN * FAN * sizeof(short);         // 102.4 MB

  short* Wbf = (short*)d_ws;
  short* vbf = (short*)((char*)d_ws + wbf_bytes);

  if (ws_size >= wbf_bytes + vbf_bytes) {
    conv_kernel<<<FAN * FAN / (256 * 8), 256, 0, stream>>>(W, Wbf);
    agg2_kernel<<<NN / 4, 256, 0, stream>>>(x, nn, nr, (unsigned short*)vbf);
    gemm_bf_kernel<<<NRB * 4, 256, 0, stream>>>(vbf, Wbf, b, out);
  } else {
    agg_fb_kernel<<<NN / 4, 256, 0, stream>>>(x, nn, nr, out);
    gemm_f32_kernel<<<(NN + 63) / 64, 256, 0, stream>>>(out, W, b, out);
  }
}

// Round 8
// 290.167 us; speedup vs baseline: 4.0290x; 4.0290x over previous
//
#include <hip/hip_runtime.h>
#include <hip/hip_bf16.h>

#define NN 100000
#define MM 32
#define NCAPS_ 8
#define HH 64
#define FAN 512  // NCAPS*H

typedef __attribute__((ext_vector_type(8))) short bf16x8;
typedef __attribute__((ext_vector_type(4))) float f32x4;
typedef __attribute__((ext_vector_type(4))) int   i32x4;

__device__ inline short f2bf(float f) {
  union { float f; unsigned u; } v; v.f = f;
  unsigned u = v.u;
  u += 0x7FFFu + ((u >> 16) & 1u);   // round-to-nearest-even
  return (short)(u >> 16);
}

__device__ inline float bf2f(unsigned short us) {
  union { unsigned u; float f; } c;
  c.u = ((unsigned)us) << 16;
  return c.f;
}

__device__ inline bf16x8 cvt8(f32x4 lo, f32x4 hi) {
  bf16x8 r;
  r[0] = f2bf(lo[0]); r[1] = f2bf(lo[1]); r[2] = f2bf(lo[2]); r[3] = f2bf(lo[3]);
  r[4] = f2bf(hi[0]); r[5] = f2bf(hi[1]); r[6] = f2bf(hi[2]); r[7] = f2bf(hi[3]);
  return r;
}

// ---------------------------------------------------------------------------
// f32 -> bf16 streaming conversion (runs at HBM BW peak)
// ---------------------------------------------------------------------------
__global__ __launch_bounds__(256) void conv_kernel(
    const float* __restrict__ src, short* __restrict__ dst) {
  const int i = (blockIdx.x * 256 + threadIdx.x) * 8;
  f32x4 lo = *(const f32x4*)(src + i);
  f32x4 hi = *(const f32x4*)(src + i + 4);
  *(bf16x8*)(dst + i) = cvt8(lo, hi);
}

// ---------------------------------------------------------------------------
// Kernel A v3: FAT-GATHER, NO CROSS-LANE REDUCE.
// One wave = 8 nodes.  lane = (ns = lane>>3: node sub-index, sub = lane&7:
// 16-B feat-chunk).  Iteration i gathers edge i of all 8 nodes with ONE
// dwordx4 instruction (eight 128-B bf16 rows).  Each lane exclusively owns
// (node, feat-chunk) -> accumulate by relation in registers via predicated
// fma into acc[8][8] (all indices compile-time).  No LDS, no atomics.
// VMEM/wave: 2 idx + 32 gather + 8 residual + 8 store = 50 for 8 nodes.
// ---------------------------------------------------------------------------
__global__ __launch_bounds__(256) void agg3_kernel(
    const unsigned short* __restrict__ xbf,
    const int* __restrict__ nb_node,
    const int* __restrict__ nb_rel,
    unsigned short* __restrict__ vbf) {
  const int tid   = threadIdx.x;
  const int wid   = tid >> 6;
  const int lane  = tid & 63;
  const int node0 = blockIdx.x * 32 + wid * 8;   // 3125 blocks * 32 == NN
  const int ns    = lane >> 3;
  const int sub   = lane & 7;
  const int node  = node0 + ns;

  // 256 (nb, rl) pairs for this wave's 8 nodes: one dwordx4 each, then pack.
  const i32x4 nb4 = ((const i32x4*)(nb_node + node0 * MM))[lane];
  const i32x4 rl4 = ((const i32x4*)(nb_rel  + node0 * MM))[lane];
  int pk[4];
#pragma unroll
  for (int j = 0; j < 4; ++j) pk[j] = nb4[j] | (rl4[j] << 20);

  float acc[NCAPS_][8];
#pragma unroll
  for (int r = 0; r < NCAPS_; ++r)
#pragma unroll
    for (int j = 0; j < 8; ++j) acc[r][j] = 0.f;

#pragma unroll
  for (int i = 0; i < MM; ++i) {
    // edge i of my node lives in lane ns*8 + i/4, component i%4 (compile-time)
    const int p  = __shfl(pk[i & 3], ns * 8 + (i >> 2));
    const int nb = p & 0xFFFFF;
    const int rl = (p >> 20) & 7;
    const bool valid = (nb < NN);
    const int nbc = valid ? nb : node;
    const bf16x8 d = *(const bf16x8*)(xbf + (size_t)nbc * FAN + rl * HH + sub * 8);
    const float mv = valid ? 1.f : 0.f;
    float v[8];
#pragma unroll
    for (int j = 0; j < 8; ++j) v[j] = bf2f((unsigned short)d[j]);
#pragma unroll
    for (int r = 0; r < NCAPS_; ++r) {
      const float mr = (rl == r) ? mv : 0.f;
#pragma unroll
      for (int j = 0; j < 8; ++j) acc[r][j] = fmaf(v[j], mr, acc[r][j]);
    }
  }

  // residual + bf16 store: lane owns feats [r*64 + sub*8, +8) of its node row
  const size_t ob = (size_t)node * FAN + sub * 8;
#pragma unroll
  for (int r = 0; r < NCAPS_; ++r) {
    const bf16x8 xr = *(const bf16x8*)(xbf + ob + r * HH);
    f32x4 lo, hi;
#pragma unroll
    for (int j = 0; j < 4; ++j) {
      lo[j] = acc[r][j]     + bf2f((unsigned short)xr[j]);
      hi[j] = acc[r][j + 4] + bf2f((unsigned short)xr[j + 4]);
    }
    *(bf16x8*)(vbf + ob + r * HH) = cvt8(lo, hi);
  }
}

// ---------------------------------------------------------------------------
// Kernel B: out = relu(vbf @ Wbf^T + b).  Round-3 measured-best config:
// BM=BN=128, BK=32 (32 KB LDS), global_load_lds double-buffer, rb-FAST
// block mapping (rb = b % NRB) -- measured 118 us vs 132 (cb-fast) / 156 (BK64).
// ---------------------------------------------------------------------------
#define BM 128
#define BN 128
#define BK 32
#define NRB ((NN + BM - 1) / BM)   // 782

__global__ __launch_bounds__(256) void gemm_bf_kernel(
    const short* __restrict__ vbf,   // [NN][FAN] bf16
    const short* __restrict__ Wbf,   // [FAN][FAN] bf16 (row-major W)
    const float* __restrict__ bias,
    float* __restrict__ out) {
  __shared__ short Ab[2][BM * BK];   // 2 x 8 KB
  __shared__ short Bb[2][BN * BK];   // 2 x 8 KB

  const int rb = blockIdx.x % NRB;
  const int cb = blockIdx.x / NRB;

  const int tid  = threadIdx.x;
  const int lane = tid & 63;
  const int wave = tid >> 6;
  const int wr = wave >> 1, wc = wave & 1;
  const int l15 = lane & 15, kg = lane >> 4;

  const int row0 = rb * BM, col0 = cb * BN;

  f32x4 acc[4][4];
#pragma unroll
  for (int rf = 0; rf < 4; ++rf)
#pragma unroll
    for (int cf = 0; cf < 4; ++cf) acc[rf][cf] = (f32x4){0.f, 0.f, 0.f, 0.f};

  auto stage = [&](int buf, int kb) {
#pragma unroll
    for (int c = 0; c < 2; ++c) {
      const int byteoff = c * 4096 + tid * 16;
      int arow = row0 + (byteoff >> 6);
      if (arow >= NN) arow = NN - 1;             // clamp (store guarded)
      const char* asrc = (const char*)vbf + (size_t)arow * 1024 + kb * 64 + (byteoff & 63);
      char* adst = (char*)(&Ab[buf][0]) + byteoff;
      __builtin_amdgcn_global_load_lds(
          (const __attribute__((address_space(1))) void*)asrc,
          (__attribute__((address_space(3))) void*)adst, 16, 0, 0);
      const int bcol = col0 + (byteoff >> 6);
      const char* bsrc = (const char*)Wbf + (size_t)bcol * 1024 + kb * 64 + (byteoff & 63);
      char* bdst = (char*)(&Bb[buf][0]) + byteoff;
      __builtin_amdgcn_global_load_lds(
          (const __attribute__((address_space(1))) void*)bsrc,
          (__attribute__((address_space(3))) void*)bdst, 16, 0, 0);
    }
  };

  stage(0, 0);
  __syncthreads();

  int buf = 0;
  for (int kb = 0; kb < FAN / BK; ++kb) {        // 16 iterations
    if (kb + 1 < FAN / BK) stage(buf ^ 1, kb + 1);

    bf16x8 af[4], bfr[4];
#pragma unroll
    for (int rf = 0; rf < 4; ++rf)
      af[rf] = *(const bf16x8*)(&Ab[buf][(wr * 64 + rf * 16 + l15) * BK + kg * 8]);
#pragma unroll
    for (int cf = 0; cf < 4; ++cf)
      bfr[cf] = *(const bf16x8*)(&Bb[buf][(wc * 64 + cf * 16 + l15) * BK + kg * 8]);

#pragma unroll
    for (int rf = 0; rf < 4; ++rf)
#pragma unroll
      for (int cf = 0; cf < 4; ++cf)
        acc[rf][cf] = __builtin_amdgcn_mfma_f32_16x16x32_bf16(
            af[rf], bfr[cf], acc[rf][cf], 0, 0, 0);

    __syncthreads();
    buf ^= 1;
  }

  // epilogue: bias + relu + store.  D: col=l15, row=kg*4+r within frag.
#pragma unroll
  for (int cf = 0; cf < 4; ++cf) {
    const int col = col0 + wc * 64 + cf * 16 + l15;
    const float bb = bias[col];
#pragma unroll
    for (int rf = 0; rf < 4; ++rf) {
#pragma unroll
      for (int r = 0; r < 4; ++r) {
        const int row = row0 + wr * 64 + rf * 16 + kg * 4 + r;
        if (row < NN) {
          float val = acc[rf][cf][r] + bb;
          out[(size_t)row * FAN + col] = val > 0.f ? val : 0.f;
        }
      }
    }
  }
}

// ---------------------------------------------------------------------------
// Fallback agg (round-6 proven): scalar addressing, 32-deep gather MLP.
// MODE 1: f32 gather -> bf16 vbf | MODE 2: f32 gather -> f32 out
// ---------------------------------------------------------------------------
template <int MODE>
__global__ __launch_bounds__(256) void agg_fb_kernel(
    const float* __restrict__ x,
    const int* __restrict__ nb_node,
    const int* __restrict__ nb_rel,
    unsigned short* __restrict__ vbf,
    float* __restrict__ vf32) {
  const int wid  = __builtin_amdgcn_readfirstlane((int)(threadIdx.x >> 6));
  const int node = blockIdx.x * 4 + wid;
  const int lane = threadIdx.x & 63;

  const int eidx = node * MM + (lane & 31);
  const int pk = nb_node[eidx] | (nb_rel[eidx] << 20);

  int nbs[MM], rls[MM];
#pragma unroll
  for (int e = 0; e < MM; ++e) {
    const int p = __builtin_amdgcn_readlane(pk, e);
    nbs[e] = p & 0xFFFFF;
    rls[e] = (p >> 20) & 7;
  }

  float vf[MM];
#pragma unroll
  for (int e = 0; e < MM; ++e) {
    const int nbc = (nbs[e] < NN) ? nbs[e] : node;
    vf[e] = x[nbc * FAN + rls[e] * HH + lane];
  }
  float xr[NCAPS_];
  const int ob = node * FAN;
#pragma unroll
  for (int r = 0; r < NCAPS_; ++r) xr[r] = x[ob + r * HH + lane];

  float acc[NCAPS_];
#pragma unroll
  for (int r = 0; r < NCAPS_; ++r) acc[r] = 0.f;
#pragma unroll
  for (int e = 0; e < MM; ++e) {
    if (nbs[e] < NN) {
      const float val = vf[e];
      switch (rls[e]) {
        case 0: acc[0] += val; break;
        case 1: acc[1] += val; break;
        case 2: acc[2] += val; break;
        case 3: acc[3] += val; break;
        case 4: acc[4] += val; break;
        case 5: acc[5] += val; break;
        case 6: acc[6] += val; break;
        case 7: acc[7] += val; break;
      }
    }
  }
#pragma unroll
  for (int r = 0; r < NCAPS_; ++r) {
    const float res = acc[r] + xr[r];
    if (MODE == 1) vbf[ob + r * HH + lane] = (unsigned short)f2bf(res);
    else           vf32[ob + r * HH + lane] = res;
  }
}

__global__ __launch_bounds__(256) void gemm_f32_kernel(
    const float* vin, const float* __restrict__ W,
    const float* __restrict__ bias, float* out) {
  const int lane = threadIdx.x & 63;
  const int wave = threadIdx.x >> 6;
  const int row0 = blockIdx.x * 64;
  const int col0 = wave * 128;
  const int l15  = lane & 15;
  const int kg   = lane >> 4;

  f32x4 acc[4][8];
#pragma unroll
  for (int rf = 0; rf < 4; ++rf)
#pragma unroll
    for (int c = 0; c < 8; ++c) acc[rf][c] = (f32x4){0.f, 0.f, 0.f, 0.f};

  for (int kb = 0; kb < FAN / 32; ++kb) {
    const int k0 = kb * 32 + kg * 8;
    bf16x8 afrag[4];
#pragma unroll
    for (int rf = 0; rf < 4; ++rf) {
      int row = row0 + rf * 16 + l15;
      if (row >= NN) row = NN - 1;
      const float* p = vin + (size_t)row * FAN + k0;
      afrag[rf] = cvt8(*(const f32x4*)p, *(const f32x4*)(p + 4));
    }
#pragma unroll
    for (int c = 0; c < 8; ++c) {
      const int col = col0 + c * 16 + l15;
      const float* q = W + (size_t)col * FAN + k0;
      bf16x8 bfrag = cvt8(*(const f32x4*)q, *(const f32x4*)(q + 4));
#pragma unroll
      for (int rf = 0; rf < 4; ++rf)
        acc[rf][c] = __builtin_amdgcn_mfma_f32_16x16x32_bf16(
            afrag[rf], bfrag, acc[rf][c], 0, 0, 0);
    }
  }

#pragma unroll
  for (int c = 0; c < 8; ++c) {
    const int col = col0 + c * 16 + l15;
    const float bb = bias[col];
#pragma unroll
    for (int rf = 0; rf < 4; ++rf)
#pragma unroll
      for (int r = 0; r < 4; ++r) {
        const int row = row0 + rf * 16 + kg * 4 + r;
        if (row < NN) {
          float val = acc[rf][c][r] + bb;
          out[(size_t)row * FAN + col] = val > 0.f ? val : 0.f;
        }
      }
  }
}

extern "C" void kernel_launch(void* const* d_in, const int* in_sizes, int n_in,
                              void* d_out, int out_size, void* d_ws, size_t ws_size,
                              hipStream_t stream) {
  const float* x  = (const float*)d_in[0];
  const float* W  = (const float*)d_in[1];
  const float* b  = (const float*)d_in[2];
  const int*   nn = (const int*)d_in[3];
  const int*   nr = (const int*)d_in[4];
  float* out = (float*)d_out;

  const size_t wbf_bytes = (size_t)FAN * FAN * sizeof(short);        // 512 KB
  const size_t vbf_bytes = (size_t)NN * FAN * sizeof(short);         // 102.4 MB
  const size_t xbf_bytes = (size_t)NN * FAN * sizeof(short);         // 102.4 MB

  short* Wbf = (short*)d_ws;
  short* vbf = (short*)((char*)d_ws + wbf_bytes);
  short* xbf = (short*)((char*)d_ws + wbf_bytes + vbf_bytes);

  if (ws_size >= wbf_bytes + vbf_bytes + xbf_bytes) {
    conv_kernel<<<FAN * FAN / (256 * 8), 256, 0, stream>>>(W, Wbf);
    conv_kernel<<<NN * FAN / (256 * 8), 256, 0, stream>>>(x, xbf);
    agg3_kernel<<<NN / 32, 256, 0, stream>>>(
        (const unsigned short*)xbf, nn, nr, (unsigned short*)vbf);
    gemm_bf_kernel<<<NRB * (FAN / BN), 256, 0, stream>>>(vbf, Wbf, b, out);
  } else if (ws_size >= wbf_bytes + vbf_bytes) {
    conv_kernel<<<FAN * FAN / (256 * 8), 256, 0, stream>>>(W, Wbf);
    agg_fb_kernel<1><<<NN / 4, 256, 0, stream>>>(
        x, nn, nr, (unsigned short*)vbf, nullptr);
    gemm_bf_kernel<<<NRB * (FAN / BN), 256, 0, stream>>>(vbf, Wbf, b, out);
  } else {
    agg_fb_kernel<2><<<NN / 4, 256, 0, stream>>>(x, nn, nr, nullptr, out);
    gemm_f32_kernel<<<(NN + 63) / 64, 256, 0, stream>>>(out, W, b, out);
  }
}